// Round 14
// baseline (196.523 us; speedup 1.0000x reference)
//
#include <hip/hip_runtime.h>
#include <math.h>
#include <stdint.h>

#define PI_F 3.14159265358979323846f

// Problem constants
#define BB 4
#define SS 4096
#define DD 1024
#define HH 16
#define DHD 64
#define NFREQ 2049   // 4096/2 + 1
#define MHALF 2048   // half-size complex FFT length

typedef unsigned short u16;
typedef __attribute__((ext_vector_type(8))) _Float16 half8;  // MFMA f16 A/B frag
typedef __attribute__((ext_vector_type(4))) float f32x4;     // MFMA C/D frag
typedef __attribute__((ext_vector_type(2))) float f32x2;     // packed-f32 complex
typedef __attribute__((ext_vector_type(4))) unsigned short u16x4;

// ---- f16 helpers (RTNE via v_cvt) ----
__device__ __forceinline__ u16 f2h(float f) {
    union { _Float16 h; u16 u; } cv;
    cv.h = (_Float16)f;
    return cv.u;
}
__device__ __forceinline__ float h2f(u16 u) {
    union { u16 u; _Float16 h; } cv;
    cv.u = u;
    return (float)cv.h;
}

__device__ __forceinline__ void modrelu_apply(float& zr, float& zi, float bias) {
    float mag = sqrtf(zr * zr + zi * zi);
    float scale = fmaxf(mag + bias, 0.0f) / fmaxf(mag, 1e-12f);
    zr *= scale; zi *= scale;
}

// async global->LDS, 16B per lane (HW: dest = wave-uniform base + lane*16)
__device__ __forceinline__ void gload16(const u16* g, u16* l) {
    __builtin_amdgcn_global_load_lds(
        (const __attribute__((address_space(1))) void*)g,
        (__attribute__((address_space(3))) void*)l, 16, 0, 0);
}

// LDS byte-offset swizzle for GEMM staging (16B chunks): XOR chunk bits [4:3]
// into chunk bits [1:0]; involution, matches the pre-swizzled staging order.
__device__ __forceinline__ int swz(int byteoff) {
    return byteoff ^ (((byteoff >> 7) & 3) << 4);
}

#define MFMA_F16 __builtin_amdgcn_mfma_f32_16x16x32_f16

// ---------------- fused x -> f16 convert + column partial sums ---------------
// grid 1024 = (b, s-chunk of 16); thread t owns columns 4t..4t+3
__global__ __launch_bounds__(256)
void split_x_colsum_kernel(const float* __restrict__ x, u16* __restrict__ xf,
                           float* __restrict__ partial) {
    int blk = blockIdx.x;
    int b = blk >> 8;
    int s0 = (blk & 255) * 16;
    int t = threadIdx.x;
    const float* xp = x + ((size_t)b * SS + s0) * DD;
    float4 acc = make_float4(0.f, 0.f, 0.f, 0.f);
    for (int s = 0; s < 16; ++s) {
        float4 v = ((const float4*)(xp + (size_t)s * DD))[t];
        acc.x += v.x; acc.y += v.y; acc.z += v.z; acc.w += v.w;
        u16x4 h;
        h.x = f2h(v.x); h.y = f2h(v.y); h.z = f2h(v.z); h.w = f2h(v.w);
        ((u16x4*)(xf + (size_t)(b * SS + s0 + s) * DD))[t] = h;
    }
    ((float4*)(partial + (size_t)blk * DD))[t] = acc;
}

// grid (4 kchunks, 4 b); sums 256 partial rows per b
__global__ __launch_bounds__(256)
void colsum2_kernel(const float* __restrict__ partial, float* __restrict__ xsum) {
    int b = blockIdx.y;
    int k = blockIdx.x * 256 + threadIdx.x;
    float acc = 0.f;
    for (int c = 0; c < 256; ++c)
        acc += partial[((size_t)(b * 256 + c)) * DD + k];
    xsum[b * DD + k] = acc;
}

// ---------------- mq[b][j] = dot(xsum[b]/S, Wq[j]) ; grid 256, 1 wave per row j
__global__ __launch_bounds__(256)
void gates1a_kernel(const float* __restrict__ xsum, const float* __restrict__ Wq,
                    float* __restrict__ mq) {
    __shared__ float xb[4][1024];
    int t = threadIdx.x;
    for (int i = t; i < 4096; i += 256)
        xb[i >> 10][i & 1023] = xsum[i] * (1.0f / 4096.0f);
    __syncthreads();
    int wv = t >> 6, l = t & 63;
    int j = blockIdx.x * 4 + wv;
    const float* wrow = Wq + (size_t)j * DD;
    float a0 = 0.f, a1 = 0.f, a2 = 0.f, a3 = 0.f;
    #pragma unroll 4
    for (int it = 0; it < 16; ++it) {
        int idx = l + it * 64;
        float wval = wrow[idx];
        a0 += xb[0][idx] * wval;
        a1 += xb[1][idx] * wval;
        a2 += xb[2][idx] * wval;
        a3 += xb[3][idx] * wval;
    }
    for (int off = 32; off > 0; off >>= 1) {
        a0 += __shfl_down(a0, off, 64);
        a1 += __shfl_down(a1, off, 64);
        a2 += __shfl_down(a2, off, 64);
        a3 += __shfl_down(a3, off, 64);
    }
    if (l == 0) {
        mq[j] = a0; mq[1024 + j] = a1; mq[2048 + j] = a2; mq[3072 + j] = a3;
    }
}

// ---------------- LayerNorm per head over mq, mean over heads -> q_shared[b][64]
__global__ __launch_bounds__(256)
void gates1b_kernel(const float* __restrict__ mq, const float* __restrict__ gamma,
                    const float* __restrict__ beta, float* __restrict__ q_shared) {
    __shared__ float qacc[4][64];
    int b = blockIdx.x;
    int t = threadIdx.x;
    int wv = t >> 6, l = t & 63;
    float part = 0.f;
    for (int hh = 0; hh < 4; ++hh) {
        int h = wv * 4 + hh;
        float v = mq[b * 1024 + h * 64 + l];
        float s1 = v, s2 = v * v;
        for (int off = 32; off > 0; off >>= 1) {
            s1 += __shfl_xor(s1, off, 64);
            s2 += __shfl_xor(s2, off, 64);
        }
        float mu = s1 * (1.0f / 64.0f);
        float var = s2 * (1.0f / 64.0f) - mu * mu;
        part += (v - mu) * rsqrtf(var + 1e-5f) * gamma[l] + beta[l];
    }
    qacc[wv][l] = part;
    __syncthreads();
    if (t < 64) {
        float s = qacc[0][t] + qacc[1][t] + qacc[2][t] + qacc[3][t];
        q_shared[b * 64 + t] = s * (1.0f / 16.0f);
    }
}

// ---------------- hdn = gelu(q_shared @ w1^T + b1)
__global__ __launch_bounds__(256)
void gates2_kernel(const float* __restrict__ q_shared, const float* __restrict__ w1,
                   const float* __restrict__ b1, float* __restrict__ hdn) {
    __shared__ float qs[64];
    int blk = blockIdx.x;
    int b = blk >> 2;
    int i0 = (blk & 3) * 256;
    int t = threadIdx.x;
    if (t < 64) qs[t] = q_shared[b * 64 + t];
    __syncthreads();
    int i = i0 + t;
    const float* wrow = w1 + (size_t)i * DHD;
    float acc = b1[i];
    #pragma unroll 8
    for (int d = 0; d < 64; ++d) acc += qs[d] * wrow[d];
    float g = 0.5f * acc * (1.0f + erff(acc * 0.70710678118654752f));
    hdn[b * DD + i] = g;
}

// ---------------- gri = hdn @ w2^T + b2 ; one wave per output row, all 4 b at once
__global__ __launch_bounds__(256)
void gates3_kernel(const float* __restrict__ hdn, const float* __restrict__ w2,
                   const float* __restrict__ b2, float* __restrict__ gri) {
    int t = threadIdx.x;
    int wv = t >> 6, l = t & 63;
    int r = blockIdx.x * 4 + wv;
    if (r >= 2 * NFREQ) return;
    const float* wrow = w2 + (size_t)r * DD;
    float a0 = 0.f, a1 = 0.f, a2 = 0.f, a3 = 0.f;
    for (int it = 0; it < 16; ++it) {
        int idx = l + it * 64;
        float wval = wrow[idx];
        a0 += hdn[idx] * wval;
        a1 += hdn[1024 + idx] * wval;
        a2 += hdn[2048 + idx] * wval;
        a3 += hdn[3072 + idx] * wval;
    }
    for (int off = 32; off > 0; off >>= 1) {
        a0 += __shfl_down(a0, off, 64);
        a1 += __shfl_down(a1, off, 64);
        a2 += __shfl_down(a2, off, 64);
        a3 += __shfl_down(a3, off, 64);
    }
    if (l == 0) {
        float bb = b2[r];
        gri[r] = a0 + bb;
        gri[2 * NFREQ + r] = a1 + bb;
        gri[2 * 2 * NFREQ + r] = a2 + bb;
        gri[3 * 2 * NFREQ + r] = a3 + bb;
    }
}

// ---------------- f32 -> f16 convert (weights) ----------------
__global__ __launch_bounds__(256)
void cvt_f16_kernel(const float* __restrict__ src, u16* __restrict__ dst, int n4) {
    int idx = blockIdx.x * 256 + threadIdx.x;
    int stride = gridDim.x * 256;
    for (; idx < n4; idx += stride) {
        float4 v = ((const float4*)src)[idx];
        u16x4 h;
        h.x = f2h(v.x); h.y = f2h(v.y); h.z = f2h(v.z); h.w = f2h(v.w);
        ((u16x4*)dst)[idx] = h;
    }
}

// ---------------- u16 transpose: src [1024][16384] -> dst [16384][1024] -------
__global__ __launch_bounds__(256)
void transpose_u16_kernel(const u16* __restrict__ src, u16* __restrict__ dst) {
    __shared__ u16 tile[64][66];
    int s0 = blockIdx.x * 64;   // bs block
    int j0 = blockIdx.y * 64;   // feature block
    int t = threadIdx.x;
    int c = t & 63, r4 = t >> 6;
    #pragma unroll
    for (int rr = 0; rr < 64; rr += 4)
        tile[rr + r4][c] = src[(size_t)(j0 + rr + r4) * 16384 + s0 + c];
    __syncthreads();
    #pragma unroll
    for (int rr = 0; rr < 64; rr += 4) {
        int a = rr + r4;                 // local bs
        dst[(size_t)(s0 + a) * 1024 + j0 + c] = tile[c][a];
    }
}

// ---------------- f16 MFMA GEMM, 128x256 tile, 256 threads, 3-deep pipeline ---
// C[M][N] = A[M][K] * B[N][K]^T ; A,B single f16 planes (row-major, stride K).
// 4 waves (1M x 4N); per-wave 128x64 out = 8x4 frags of 16x16x32 (identical
// inner loop + vmcnt discipline to the R8-verified 256x256 kernel; geometry
// shrunk so LDS = 3 buf x 24KB = 72KB and VGPR ~170 -> TWO blocks per CU.
// Co-resident blocks with independent barriers interleave: one block's
// stage-wait overlaps the other's MFMA (m114 wave-level overlap).
template <bool F16OUT>
__global__ __launch_bounds__(256, 2)
void gemm_f16_kernel(const u16* __restrict__ A, const u16* __restrict__ B,
                     void* __restrict__ Cv, int mtiles, int ntiles, int K, int ldc) {
    __shared__ u16 lds[3][12288];   // [buf][A:128x32 | B:256x32]
    const int t = threadIdx.x;
    const int wid = __builtin_amdgcn_readfirstlane(t >> 6);
    const int lane = t & 63;

    // XCD-aware decode (blocks dispatch round-robin over 8 XCDs)
    const int bid = blockIdx.x;
    const int xcd = bid & 7;
    const int idx = bid >> 3;
    int mt, nt;
    if (ntiles >= mtiles) { mt = idx % mtiles; nt = xcd * (ntiles >> 3) + idx / mtiles; }
    else                  { nt = idx % ntiles; mt = xcd * (mtiles >> 3) + idx / ntiles; }
    const int m0 = mt * 128;
    const int n0 = nt * 256;
    const int wn = wid * 64;

    // staging: 24 chunk-ops of 1KB per tile (wave w gets ops g = w*6..w*6+5)
    // g<8 -> A plane (512 chunks), else B plane (1024 chunks)
    const u16* gbase[6];
    u16* ldst[6];
    #pragma unroll
    for (int o = 0; o < 6; ++o) {
        int g = wid * 6 + o;
        bool isA = (g < 8);
        int j = isA ? (g * 64 + lane) : ((g - 8) * 64 + lane);
        int c = j ^ ((j >> 3) & 3);
        int row = c >> 2, q = c & 3;
        const u16* base = isA ? A : B;
        int rbase = isA ? m0 : n0;
        gbase[o] = base + (size_t)(rbase + row) * K + q * 8;
        ldst[o] = &lds[0][0] + (isA ? 0 : 4096) + (size_t)j * 8;
    }

#define STG(KT, BUF)                                                             \
    {                                                                            \
        _Pragma("unroll")                                                        \
        for (int o = 0; o < 6; ++o)                                              \
            gload16(gbase[o] + (size_t)(KT) * 32, ldst[o] + (BUF) * 12288);      \
    }

    f32x4 acc[8][4] = {};
    const int KT = K >> 5;

    // prologue: stage tiles 0 and 1; wait for tile 0 only (6 newest may fly)
    STG(0, 0);
    STG(1, 1);
    asm volatile("s_waitcnt vmcnt(6)" ::: "memory");
    __builtin_amdgcn_s_barrier();

    for (int kt = 0; kt < KT; ++kt) {
        const u16* lb = &lds[kt % 3][0];
        // issue stage for tile kt+2 first: longest latency cover
        if (kt + 2 < KT) STG(kt + 2, (kt + 2) % 3);

        half8 b[4];
        #pragma unroll
        for (int j = 0; j < 4; ++j) {
            int s = swz((wn + (lane & 15) + j * 16) * 64 + (lane >> 4) * 16);
            b[j] = *(const half8*)(lb + 4096 + (s >> 1));
        }
        __builtin_amdgcn_s_setprio(1);
        #pragma unroll
        for (int ip = 0; ip < 4; ++ip) {
            int s0 = swz(((lane & 15) + (2 * ip) * 16) * 64 + (lane >> 4) * 16);
            int s1 = swz(((lane & 15) + (2 * ip + 1) * 16) * 64 + (lane >> 4) * 16);
            half8 a0 = *(const half8*)(lb + (s0 >> 1));
            half8 a1 = *(const half8*)(lb + (s1 >> 1));
            #pragma unroll
            for (int j = 0; j < 4; ++j) acc[2 * ip][j]     = MFMA_F16(a0, b[j], acc[2 * ip][j], 0, 0, 0);
            #pragma unroll
            for (int j = 0; j < 4; ++j) acc[2 * ip + 1][j] = MFMA_F16(a1, b[j], acc[2 * ip + 1][j], 0, 0, 0);
        }
        __builtin_amdgcn_s_setprio(0);
        // make buffer kt+1 ready: wait until only tile kt+2's 6 loads remain
        if (kt + 2 < KT) { asm volatile("s_waitcnt vmcnt(6)" ::: "memory"); }
        else             { asm volatile("s_waitcnt vmcnt(0)" ::: "memory"); }
        __builtin_amdgcn_s_barrier();
    }
#undef STG

    // epilogue: C/D layout = col (lane&15), row (lane>>4)*4 + e   [m89-verified]
    const int cb2 = n0 + wn + (lane & 15);
    #pragma unroll
    for (int i = 0; i < 8; ++i) {
        int rb = m0 + i * 16 + ((lane >> 4) << 2);
        #pragma unroll
        for (int e = 0; e < 4; ++e) {
            if (F16OUT) {
                u16* crow = (u16*)Cv + (size_t)(rb + e) * ldc + cb2;
                #pragma unroll
                for (int j = 0; j < 4; ++j)
                    crow[j * 16] = f2h(acc[i][j][e]);
            } else {
                float* crow = (float*)Cv + (size_t)(rb + e) * ldc + cb2;
                #pragma unroll
                for (int j = 0; j < 4; ++j)
                    crow[j * 16] = acc[i][j][e];
            }
        }
    }
}

// ---------------- twiddle table init (global, shared by all FFT blocks) -------
__global__ __launch_bounds__(256)
void twiddle_init_kernel(float2* __restrict__ Tg) {
    int idx = blockIdx.x * 256 + threadIdx.x;
    if (idx >= 3072) return;
    float cs = 1.f, sn = 0.f;
    if (idx >= 2048) {
        sincosf(PI_F * (float)(idx - 2048) * (1.0f / 2048.0f), &sn, &cs);
    } else if (idx >= 1) {
        int s = 31 - __clz(idx);
        int h = 1 << s;
        sincosf(PI_F * (float)(idx - h) / (float)h, &sn, &cs);
    }
    Tg[idx] = make_float2(cs, sn);
}

// ---- packed-f32 butterflies: a,b are (re,im); compiles to v_pk_*_f32 ----
__device__ __forceinline__ void bfly_f(f32x2& a, f32x2& b, float cs, float sn) {
    f32x2 s = a + b;
    f32x2 d = a - b;
    f32x2 dsw = __builtin_shufflevector(d, d, 1, 0);   // (im, re)
    a = s;
    b = d * cs + dsw * (f32x2){sn, -sn};   // (dr*cs+di*sn, di*cs-dr*sn)
}
__device__ __forceinline__ void bfly_i(f32x2& a, f32x2& b, float cs, float sn) {
    f32x2 bsw = __builtin_shufflevector(b, b, 1, 0);   // (im, re)
    f32x2 c = b * cs + bsw * (f32x2){-sn, sn};         // b * e^{+i th}
    b = a - c;
    a = a + c;
}
// pad-based LDS index map: 2 float2 of pad per 32 elements.
__device__ __forceinline__ int IDX(int a) { return a + 2 * (a >> 5); }

// ---------------- fused rfft -> gates -> modReLU -> irfft, in-place f16 ------
__global__ __launch_bounds__(256)
void fft_gates_kernel(u16* __restrict__ vbuf, const float* __restrict__ gri,
                      const float* __restrict__ modb, const float2* __restrict__ Tg) {
    __shared__ f32x2 cf[2176];   // 2048 + 128 pad
    const int t = threadIdx.x;
    const int w = blockIdx.x;
    const int b = w & 3;
    u16* seq = vbuf + (size_t)w * SS;

    const int t5 = t & 31;
    const int t3 = t & 3;
    const int c32 = ((t >> 5) << 8) | t5;    // base for 32-span group
    const int d4  = ((t >> 2) << 5) | t3;    // base for 4-span group

    f32x2 r[8];

    // ---- load (f16 pairs) + G1: stages 10,9,8 (span 256) ----
    #pragma unroll
    for (int u = 0; u < 8; ++u) {
        ushort2 v = ((const ushort2*)seq)[t + 256 * u];
        r[u] = (f32x2){h2f(v.x), h2f(v.y)};
    }
    #pragma unroll
    for (int u = 0; u < 4; ++u) {
        float2 tw = Tg[1024 + t + 256 * u];
        bfly_f(r[u], r[u + 4], tw.x, tw.y);
    }
    {
        float2 tw0 = Tg[512 + t], tw1 = Tg[512 + t + 256];
        bfly_f(r[0], r[2], tw0.x, tw0.y);
        bfly_f(r[1], r[3], tw1.x, tw1.y);
        bfly_f(r[4], r[6], tw0.x, tw0.y);
        bfly_f(r[5], r[7], tw1.x, tw1.y);
        float2 tw = Tg[256 + t];
        bfly_f(r[0], r[1], tw.x, tw.y);
        bfly_f(r[2], r[3], tw.x, tw.y);
        bfly_f(r[4], r[5], tw.x, tw.y);
        bfly_f(r[6], r[7], tw.x, tw.y);
    }
    #pragma unroll
    for (int u = 0; u < 8; ++u) cf[IDX(t + 256 * u)] = r[u];
    __syncthreads();

    // ---- G2: stages 7,6,5 (span 32) ----
    #pragma unroll
    for (int u = 0; u < 8; ++u) r[u] = cf[IDX(c32 + 32 * u)];
    #pragma unroll
    for (int u = 0; u < 4; ++u) {
        float2 tw = Tg[128 + t5 + 32 * u];
        bfly_f(r[u], r[u + 4], tw.x, tw.y);
    }
    {
        float2 tw0 = Tg[64 + t5], tw1 = Tg[64 + t5 + 32];
        bfly_f(r[0], r[2], tw0.x, tw0.y);
        bfly_f(r[1], r[3], tw1.x, tw1.y);
        bfly_f(r[4], r[6], tw0.x, tw0.y);
        bfly_f(r[5], r[7], tw1.x, tw1.y);
        float2 tw = Tg[32 + t5];
        bfly_f(r[0], r[1], tw.x, tw.y);
        bfly_f(r[2], r[3], tw.x, tw.y);
        bfly_f(r[4], r[5], tw.x, tw.y);
        bfly_f(r[6], r[7], tw.x, tw.y);
    }
    #pragma unroll
    for (int u = 0; u < 8; ++u) cf[IDX(c32 + 32 * u)] = r[u];
    __syncthreads();

    // ---- G3: stages 4,3,2 (span 4) ----
    {
        f32x2* p3 = &cf[IDX(d4)];
        #pragma unroll
        for (int u = 0; u < 8; ++u) r[u] = p3[4 * u];
        #pragma unroll
        for (int u = 0; u < 4; ++u) {
            float2 tw = Tg[16 + t3 + 4 * u];
            bfly_f(r[u], r[u + 4], tw.x, tw.y);
        }
        {
            float2 tw0 = Tg[8 + t3], tw1 = Tg[8 + t3 + 4];
            bfly_f(r[0], r[2], tw0.x, tw0.y);
            bfly_f(r[1], r[3], tw1.x, tw1.y);
            bfly_f(r[4], r[6], tw0.x, tw0.y);
            bfly_f(r[5], r[7], tw1.x, tw1.y);
            float2 tw = Tg[4 + t3];
            bfly_f(r[0], r[1], tw.x, tw.y);
            bfly_f(r[2], r[3], tw.x, tw.y);
            bfly_f(r[4], r[5], tw.x, tw.y);
            bfly_f(r[6], r[7], tw.x, tw.y);
        }
        #pragma unroll
        for (int u = 0; u < 8; ++u) p3[4 * u] = r[u];
    }
    __syncthreads();

    // ---- G4: stages 1,0 (span 1; 8 consecutive -> b128-able) ----
    {
        f32x2* p4 = &cf[IDX(8 * t)];
        #pragma unroll
        for (int u = 0; u < 8; ++u) r[u] = p4[u];
        bfly_f(r[0], r[2], 1.f, 0.f);
        bfly_f(r[1], r[3], 0.f, 1.f);
        bfly_f(r[4], r[6], 1.f, 0.f);
        bfly_f(r[5], r[7], 0.f, 1.f);
        bfly_f(r[0], r[1], 1.f, 0.f);
        bfly_f(r[2], r[3], 1.f, 0.f);
        bfly_f(r[4], r[5], 1.f, 0.f);
        bfly_f(r[6], r[7], 1.f, 0.f);
        #pragma unroll
        for (int u = 0; u < 8; ++u) p4[u] = r[u];
    }
    __syncthreads();

    // ---- spectrum: unpack real-FFT bins (ortho /64), gates, modReLU, repack ----
    const float bias = modb[0];
    const float* gre = gri + (size_t)b * 2 * NFREQ;
    const float* gim = gre + NFREQ;
    const float inv64 = 1.0f / 64.0f;
    for (int k = t; k < 1024; k += 256) {
        if (k == 0) {
            f32x2 c0 = cf[IDX(0)];
            float z0 = (c0.x + c0.y) * inv64;
            float zM = (c0.x - c0.y) * inv64;
            float zr = z0 * gre[0], zi = z0 * gim[0];
            modrelu_apply(zr, zi, bias);
            float yr = zM * gre[2048], yi = zM * gim[2048];
            modrelu_apply(yr, yi, bias);
            cf[IDX(0)] = (f32x2){0.5f * (zr + yr), 0.5f * (zr - yr)};
            f32x2 c1 = cf[IDX(1)];
            float z1r = c1.x * inv64, z1i = -c1.y * inv64;
            float g1r = gre[1024], g1i = gim[1024];
            float pr = z1r * g1r - z1i * g1i;
            float pi2 = z1r * g1i + z1i * g1r;
            modrelu_apply(pr, pi2, bias);
            cf[IDX(1)] = (f32x2){pr, -pi2};
        } else {
            int kb = 2048 - k;
            int p1 = IDX((int)(__brev((unsigned)k) >> 21));
            int p2 = IDX((int)(__brev((unsigned)kb) >> 21));
            f32x2 ca = cf[p1];
            f32x2 cb2 = cf[p2];
            float Er = 0.5f * (ca.x + cb2.x), Ei = 0.5f * (ca.y - cb2.y);
            float Dr = 0.5f * (ca.x - cb2.x), Di = 0.5f * (ca.y + cb2.y);
            float Or = Di, Oi = -Dr;
            float2 t2 = Tg[2048 + k];
            float cs = t2.x, sn = t2.y;
            float Wr = cs, Wi = -sn;
            float WOr = Wr * Or - Wi * Oi, WOi = Wr * Oi + Wi * Or;
            float zkr = (Er + WOr) * inv64, zki = (Ei + WOi) * inv64;
            float zbr = (Er - WOr) * inv64, zbi = -(Ei - WOi) * inv64;
            float gkr = gre[k], gki = gim[k];
            float ar = zkr * gkr - zki * gki, ai = zkr * gki + zki * gkr;
            modrelu_apply(ar, ai, bias);
            float gbr = gre[kb], gbi = gim[kb];
            float br2 = zbr * gbr - zbi * gbi, bi2 = zbr * gbi + zbi * gbr;
            modrelu_apply(br2, bi2, bias);
            float Epr = 0.5f * (ar + br2), Epi = 0.5f * (ai - bi2);
            float Dpr = 0.5f * (ar - br2), Dpi = 0.5f * (ai + bi2);
            float Opr = cs * Dpr - sn * Dpi, Opi = cs * Dpi + sn * Dpr;
            cf[p1] = (f32x2){Epr - Opi, Epi + Opr};
            cf[p2] = (f32x2){Epr + Opi, -Epi + Opr};
        }
    }
    __syncthreads();

    // ---- inverse G4': stages 0,1 ----
    {
        f32x2* p4 = &cf[IDX(8 * t)];
        #pragma unroll
        for (int u = 0; u < 8; ++u) r[u] = p4[u];
        bfly_i(r[0], r[1], 1.f, 0.f);
        bfly_i(r[2], r[3], 1.f, 0.f);
        bfly_i(r[4], r[5], 1.f, 0.f);
        bfly_i(r[6], r[7], 1.f, 0.f);
        bfly_i(r[0], r[2], 1.f, 0.f);
        bfly_i(r[1], r[3], 0.f, 1.f);
        bfly_i(r[4], r[6], 1.f, 0.f);
        bfly_i(r[5], r[7], 0.f, 1.f);
        #pragma unroll
        for (int u = 0; u < 8; ++u) p4[u] = r[u];
    }
    __syncthreads();

    // ---- inverse G3': stages 2,3,4 ----
    {
        f32x2* p3 = &cf[IDX(d4)];
        #pragma unroll
        for (int u = 0; u < 8; ++u) r[u] = p3[4 * u];
        {
            float2 tw = Tg[4 + t3];
            bfly_i(r[0], r[1], tw.x, tw.y);
            bfly_i(r[2], r[3], tw.x, tw.y);
            bfly_i(r[4], r[5], tw.x, tw.y);
            bfly_i(r[6], r[7], tw.x, tw.y);
            float2 tw0 = Tg[8 + t3], tw1 = Tg[8 + t3 + 4];
            bfly_i(r[0], r[2], tw0.x, tw0.y);
            bfly_i(r[1], r[3], tw1.x, tw1.y);
            bfly_i(r[4], r[6], tw0.x, tw0.y);
            bfly_i(r[5], r[7], tw1.x, tw1.y);
        }
        #pragma unroll
        for (int u = 0; u < 4; ++u) {
            float2 tw = Tg[16 + t3 + 4 * u];
            bfly_i(r[u], r[u + 4], tw.x, tw.y);
        }
        #pragma unroll
        for (int u = 0; u < 8; ++u) p3[4 * u] = r[u];
    }
    __syncthreads();

    // ---- inverse G2': stages 5,6,7 ----
    #pragma unroll
    for (int u = 0; u < 8; ++u) r[u] = cf[IDX(c32 + 32 * u)];
    {
        float2 tw = Tg[32 + t5];
        bfly_i(r[0], r[1], tw.x, tw.y);
        bfly_i(r[2], r[3], tw.x, tw.y);
        bfly_i(r[4], r[5], tw.x, tw.y);
        bfly_i(r[6], r[7], tw.x, tw.y);
        float2 tw0 = Tg[64 + t5], tw1 = Tg[64 + t5 + 32];
        bfly_i(r[0], r[2], tw0.x, tw0.y);
        bfly_i(r[1], r[3], tw1.x, tw1.y);
        bfly_i(r[4], r[6], tw0.x, tw0.y);
        bfly_i(r[5], r[7], tw1.x, tw1.y);
    }
    #pragma unroll
    for (int u = 0; u < 4; ++u) {
        float2 tw = Tg[128 + t5 + 32 * u];
        bfly_i(r[u], r[u + 4], tw.x, tw.y);
    }
    #pragma unroll
    for (int u = 0; u < 8; ++u) cf[IDX(c32 + 32 * u)] = r[u];
    __syncthreads();

    // ---- inverse G1': stages 8,9,10 + scale + f16 store ----
    #pragma unroll
    for (int u = 0; u < 8; ++u) r[u] = cf[IDX(t + 256 * u)];
    {
        float2 tw = Tg[256 + t];
        bfly_i(r[0], r[1], tw.x, tw.y);
        bfly_i(r[2], r[3], tw.x, tw.y);
        bfly_i(r[4], r[5], tw.x, tw.y);
        bfly_i(r[6], r[7], tw.x, tw.y);
        float2 tw0 = Tg[512 + t], tw1 = Tg[512 + t + 256];
        bfly_i(r[0], r[2], tw0.x, tw0.y);
        bfly_i(r[1], r[3], tw1.x, tw1.y);
        bfly_i(r[4], r[6], tw0.x, tw0.y);
        bfly_i(r[5], r[7], tw1.x, tw1.y);
    }
    #pragma unroll
    for (int u = 0; u < 4; ++u) {
        float2 tw = Tg[1024 + t + 256 * u];
        bfly_i(r[u], r[u + 4], tw.x, tw.y);
    }
    const float s32 = 1.0f / 32.0f;  // 64 (ortho) / 2048 (ifft norm)
    #pragma unroll
    for (int u = 0; u < 8; ++u) {
        ushort2 o;
        o.x = f2h(r[u].x * s32);
        o.y = f2h(r[u].y * s32);
        ((ushort2*)seq)[t + 256 * u] = o;
    }
}

extern "C" void kernel_launch(void* const* d_in, const int* in_sizes, int n_in,
                              void* d_out, int out_size, void* d_ws, size_t ws_size,
                              hipStream_t stream) {
    const float* x        = (const float*)d_in[0];
    const float* W_q      = (const float*)d_in[1];
    const float* W_v      = (const float*)d_in[2];
    const float* W_o      = (const float*)d_in[3];
    const float* ln_gamma = (const float*)d_in[4];
    const float* ln_beta  = (const float*)d_in[5];
    const float* mlp_w1   = (const float*)d_in[6];
    const float* mlp_b1   = (const float*)d_in[7];
    const float* mlp_w2   = (const float*)d_in[8];
    const float* mlp_b2   = (const float*)d_in[9];
    const float* mod_bias = (const float*)d_in[10];
    float* out = (float*)d_out;

    // workspace layout (floats)
    float* ws = (float*)d_ws;
    float* partial  = ws;                    // 1048576 (1024 blocks x 1024)
    float* xsum     = ws + 1048576;          // 4096
    float* q_shared = ws + 1052672;          // 256
    float* hdn      = ws + 1052928;          // 4096
    float* gri      = ws + 1057024;          // 16392
    float* mq       = ws + 1073416;          // 4096 (ends 1077512)
    float2* twid    = (float2*)(ws + 1077512); // 3072 float2 (ends 1083656)
    u16* bfbase = (u16*)(ws + 1083904);
    u16* xut_f  = bfbase;                    // 16777216 u16: x_f16, later reused as ut
    u16* vbuf   = bfbase + 16777216;         // f16 V then u, [1024][16384] in-place fft
    u16* wv_f   = bfbase + 33554432;         // 1048576
    u16* wo_f   = bfbase + 34603008;         // 1048576

    twiddle_init_kernel<<<12, 256, 0, stream>>>(twid);

    // fused x f16-convert + colsum pass 1
    split_x_colsum_kernel<<<1024, 256, 0, stream>>>(x, xut_f, partial);
    {
        dim3 g(4, 4);
        colsum2_kernel<<<g, 256, 0, stream>>>(partial, xsum);
    }
    gates1a_kernel<<<256, 256, 0, stream>>>(xsum, W_q, mq);
    gates1b_kernel<<<4, 256, 0, stream>>>(mq, ln_gamma, ln_beta, q_shared);
    gates2_kernel<<<16, 256, 0, stream>>>(q_shared, mlp_w1, mlp_b1, hdn);
    gates3_kernel<<<1025, 256, 0, stream>>>(hdn, mlp_w2, mlp_b2, gri);

    // weight f16 conversions
    cvt_f16_kernel<<<512, 256, 0, stream>>>(W_v, wv_f, 262144);
    cvt_f16_kernel<<<512, 256, 0, stream>>>(W_o, wo_f, 262144);

    // V projection (transposed output), f16 in/out: vbuf[j][bs] = Wv[j,:]·x[bs,:]
    // M=1024 (j): mtiles=8; N=16384 (bs): ntiles=64 -> 512 blocks (2/CU)
    gemm_f16_kernel<true><<<512, 256, 0, stream>>>(wv_f, xut_f,
                                                   vbuf, 8, 64, 1024, 16384);

    // fused spectral mixing, in place on vbuf (f16 -> f16)
    fft_gates_kernel<<<4096, 256, 0, stream>>>(vbuf, gri, mod_bias, twid);

    // transpose u: vbuf [1024][16384] -> xut_f [16384][1024] (pure u16 permute)
    {
        dim3 g(256, 16);
        transpose_u16_kernel<<<g, 256, 0, stream>>>(vbuf, xut_f);
    }

    // O projection, f16 in / f32 out: out[bs][jo] = ut[bs,:]·Wo[jo,:]
    // M=16384 (bs): mtiles=128; N=1024 (jo): ntiles=4 -> 512 blocks (2/CU)
    gemm_f16_kernel<false><<<512, 256, 0, stream>>>(xut_f, wo_f,
                                                    out, 128, 4, 1024, 1024);
}

// Round 15
// 190.503 us; speedup vs baseline: 1.0316x; 1.0316x over previous
//
#include <hip/hip_runtime.h>
#include <math.h>
#include <stdint.h>

#define PI_F 3.14159265358979323846f

// Problem constants
#define BB 4
#define SS 4096
#define DD 1024
#define HH 16
#define DHD 64
#define NFREQ 2049   // 4096/2 + 1
#define MHALF 2048   // half-size complex FFT length

typedef unsigned short u16;
typedef __attribute__((ext_vector_type(8))) _Float16 half8;  // MFMA f16 A/B frag
typedef __attribute__((ext_vector_type(4))) float f32x4;     // MFMA C/D frag
typedef __attribute__((ext_vector_type(2))) float f32x2;     // packed-f32 complex
typedef __attribute__((ext_vector_type(4))) unsigned short u16x4;

// ---- f16 helpers (RTNE via v_cvt) ----
__device__ __forceinline__ u16 f2h(float f) {
    union { _Float16 h; u16 u; } cv;
    cv.h = (_Float16)f;
    return cv.u;
}
__device__ __forceinline__ float h2f(u16 u) {
    union { u16 u; _Float16 h; } cv;
    cv.u = u;
    return (float)cv.h;
}

__device__ __forceinline__ void modrelu_apply(float& zr, float& zi, float bias) {
    float mag = sqrtf(zr * zr + zi * zi);
    float scale = fmaxf(mag + bias, 0.0f) / fmaxf(mag, 1e-12f);
    zr *= scale; zi *= scale;
}

// async global->LDS, 16B per lane (HW: dest = wave-uniform base + lane*16)
__device__ __forceinline__ void gload16(const u16* g, u16* l) {
    __builtin_amdgcn_global_load_lds(
        (const __attribute__((address_space(1))) void*)g,
        (__attribute__((address_space(3))) void*)l, 16, 0, 0);
}

// LDS byte-offset swizzle for GEMM staging (16B chunks): XOR chunk bits [4:3]
// into chunk bits [1:0]; involution, matches the pre-swizzled staging order.
__device__ __forceinline__ int swz(int byteoff) {
    return byteoff ^ (((byteoff >> 7) & 3) << 4);
}

#define MFMA_F16 __builtin_amdgcn_mfma_f32_16x16x32_f16

// ---------------- fused x -> f16 convert + column partial sums ---------------
// grid 1024 = (b, s-chunk of 16); thread t owns columns 4t..4t+3
__global__ __launch_bounds__(256)
void split_x_colsum_kernel(const float* __restrict__ x, u16* __restrict__ xf,
                           float* __restrict__ partial) {
    int blk = blockIdx.x;
    int b = blk >> 8;
    int s0 = (blk & 255) * 16;
    int t = threadIdx.x;
    const float* xp = x + ((size_t)b * SS + s0) * DD;
    float4 acc = make_float4(0.f, 0.f, 0.f, 0.f);
    for (int s = 0; s < 16; ++s) {
        float4 v = ((const float4*)(xp + (size_t)s * DD))[t];
        acc.x += v.x; acc.y += v.y; acc.z += v.z; acc.w += v.w;
        u16x4 h;
        h.x = f2h(v.x); h.y = f2h(v.y); h.z = f2h(v.z); h.w = f2h(v.w);
        ((u16x4*)(xf + (size_t)(b * SS + s0 + s) * DD))[t] = h;
    }
    ((float4*)(partial + (size_t)blk * DD))[t] = acc;
}

// grid (4 kchunks, 4 b); sums 256 partial rows per b
__global__ __launch_bounds__(256)
void colsum2_kernel(const float* __restrict__ partial, float* __restrict__ xsum) {
    int b = blockIdx.y;
    int k = blockIdx.x * 256 + threadIdx.x;
    float acc = 0.f;
    for (int c = 0; c < 256; ++c)
        acc += partial[((size_t)(b * 256 + c)) * DD + k];
    xsum[b * DD + k] = acc;
}

// ---------------- mq[b][j] = dot(xsum[b]/S, Wq[j]) ; grid 256, 1 wave per row j
__global__ __launch_bounds__(256)
void gates1a_kernel(const float* __restrict__ xsum, const float* __restrict__ Wq,
                    float* __restrict__ mq) {
    __shared__ float xb[4][1024];
    int t = threadIdx.x;
    for (int i = t; i < 4096; i += 256)
        xb[i >> 10][i & 1023] = xsum[i] * (1.0f / 4096.0f);
    __syncthreads();
    int wv = t >> 6, l = t & 63;
    int j = blockIdx.x * 4 + wv;
    const float* wrow = Wq + (size_t)j * DD;
    float a0 = 0.f, a1 = 0.f, a2 = 0.f, a3 = 0.f;
    #pragma unroll 4
    for (int it = 0; it < 16; ++it) {
        int idx = l + it * 64;
        float wval = wrow[idx];
        a0 += xb[0][idx] * wval;
        a1 += xb[1][idx] * wval;
        a2 += xb[2][idx] * wval;
        a3 += xb[3][idx] * wval;
    }
    for (int off = 32; off > 0; off >>= 1) {
        a0 += __shfl_down(a0, off, 64);
        a1 += __shfl_down(a1, off, 64);
        a2 += __shfl_down(a2, off, 64);
        a3 += __shfl_down(a3, off, 64);
    }
    if (l == 0) {
        mq[j] = a0; mq[1024 + j] = a1; mq[2048 + j] = a2; mq[3072 + j] = a3;
    }
}

// ---------------- LayerNorm per head over mq, mean over heads -> q_shared[b][64]
__global__ __launch_bounds__(256)
void gates1b_kernel(const float* __restrict__ mq, const float* __restrict__ gamma,
                    const float* __restrict__ beta, float* __restrict__ q_shared) {
    __shared__ float qacc[4][64];
    int b = blockIdx.x;
    int t = threadIdx.x;
    int wv = t >> 6, l = t & 63;
    float part = 0.f;
    for (int hh = 0; hh < 4; ++hh) {
        int h = wv * 4 + hh;
        float v = mq[b * 1024 + h * 64 + l];
        float s1 = v, s2 = v * v;
        for (int off = 32; off > 0; off >>= 1) {
            s1 += __shfl_xor(s1, off, 64);
            s2 += __shfl_xor(s2, off, 64);
        }
        float mu = s1 * (1.0f / 64.0f);
        float var = s2 * (1.0f / 64.0f) - mu * mu;
        part += (v - mu) * rsqrtf(var + 1e-5f) * gamma[l] + beta[l];
    }
    qacc[wv][l] = part;
    __syncthreads();
    if (t < 64) {
        float s = qacc[0][t] + qacc[1][t] + qacc[2][t] + qacc[3][t];
        q_shared[b * 64 + t] = s * (1.0f / 16.0f);
    }
}

// ---------------- hdn = gelu(q_shared @ w1^T + b1)
__global__ __launch_bounds__(256)
void gates2_kernel(const float* __restrict__ q_shared, const float* __restrict__ w1,
                   const float* __restrict__ b1, float* __restrict__ hdn) {
    __shared__ float qs[64];
    int blk = blockIdx.x;
    int b = blk >> 2;
    int i0 = (blk & 3) * 256;
    int t = threadIdx.x;
    if (t < 64) qs[t] = q_shared[b * 64 + t];
    __syncthreads();
    int i = i0 + t;
    const float* wrow = w1 + (size_t)i * DHD;
    float acc = b1[i];
    #pragma unroll 8
    for (int d = 0; d < 64; ++d) acc += qs[d] * wrow[d];
    float g = 0.5f * acc * (1.0f + erff(acc * 0.70710678118654752f));
    hdn[b * DD + i] = g;
}

// ---------------- gri = hdn @ w2^T + b2 ; one wave per output row, all 4 b at once
__global__ __launch_bounds__(256)
void gates3_kernel(const float* __restrict__ hdn, const float* __restrict__ w2,
                   const float* __restrict__ b2, float* __restrict__ gri) {
    int t = threadIdx.x;
    int wv = t >> 6, l = t & 63;
    int r = blockIdx.x * 4 + wv;
    if (r >= 2 * NFREQ) return;
    const float* wrow = w2 + (size_t)r * DD;
    float a0 = 0.f, a1 = 0.f, a2 = 0.f, a3 = 0.f;
    for (int it = 0; it < 16; ++it) {
        int idx = l + it * 64;
        float wval = wrow[idx];
        a0 += hdn[idx] * wval;
        a1 += hdn[1024 + idx] * wval;
        a2 += hdn[2048 + idx] * wval;
        a3 += hdn[3072 + idx] * wval;
    }
    for (int off = 32; off > 0; off >>= 1) {
        a0 += __shfl_down(a0, off, 64);
        a1 += __shfl_down(a1, off, 64);
        a2 += __shfl_down(a2, off, 64);
        a3 += __shfl_down(a3, off, 64);
    }
    if (l == 0) {
        float bb = b2[r];
        gri[r] = a0 + bb;
        gri[2 * NFREQ + r] = a1 + bb;
        gri[2 * 2 * NFREQ + r] = a2 + bb;
        gri[3 * 2 * NFREQ + r] = a3 + bb;
    }
}

// ---------------- f32 -> f16 convert, both weight matrices in one launch ------
__global__ __launch_bounds__(256)
void cvt_f16_dual_kernel(const float* __restrict__ s0, u16* __restrict__ d0,
                         const float* __restrict__ s1, u16* __restrict__ d1,
                         int n4each) {
    int half = gridDim.x >> 1;
    const float* src = (blockIdx.x < half) ? s0 : s1;
    u16* dst = (blockIdx.x < half) ? d0 : d1;
    int bid = (blockIdx.x < half) ? blockIdx.x : blockIdx.x - half;
    int idx = bid * 256 + threadIdx.x;
    int stride = half * 256;
    for (; idx < n4each; idx += stride) {
        float4 v = ((const float4*)src)[idx];
        u16x4 h;
        h.x = f2h(v.x); h.y = f2h(v.y); h.z = f2h(v.z); h.w = f2h(v.w);
        ((u16x4*)dst)[idx] = h;
    }
}

// ---------------- u16 transpose: src [1024][16384] -> dst [16384][1024] -------
__global__ __launch_bounds__(256)
void transpose_u16_kernel(const u16* __restrict__ src, u16* __restrict__ dst) {
    __shared__ u16 tile[64][66];
    int s0 = blockIdx.x * 64;   // bs block
    int j0 = blockIdx.y * 64;   // feature block
    int t = threadIdx.x;
    int c = t & 63, r4 = t >> 6;
    #pragma unroll
    for (int rr = 0; rr < 64; rr += 4)
        tile[rr + r4][c] = src[(size_t)(j0 + rr + r4) * 16384 + s0 + c];
    __syncthreads();
    #pragma unroll
    for (int rr = 0; rr < 64; rr += 4) {
        int a = rr + r4;                 // local bs
        dst[(size_t)(s0 + a) * 1024 + j0 + c] = tile[c][a];
    }
}

// ---------------- f16 single-product MFMA GEMM, 256x256 tile, 4-deep pipeline -
// [R13-measured config: ~46 us/dispatch. R6/R7/R9/R14 structural variants all
//  regressed -- this is the settled GEMM. Do not modify.]
template <bool F16OUT>
__global__ __launch_bounds__(512, 2)
void gemm_f16_kernel(const u16* __restrict__ A, const u16* __restrict__ B,
                     void* __restrict__ Cv, int mtiles, int ntiles, int K, int ldc) {
    __shared__ u16 lds[4][2][8192];   // [buf][plane: A,B][256 rows x 32 k]
    const int t = threadIdx.x;
    const int wid = __builtin_amdgcn_readfirstlane(t >> 6);
    const int lane = t & 63;

    // XCD-aware decode (blocks dispatch round-robin over 8 XCDs)
    const int bid = blockIdx.x;
    const int xcd = bid & 7;
    const int idx = bid >> 3;
    int mt, nt;
    if (ntiles >= mtiles) { mt = idx % mtiles; nt = xcd * (ntiles >> 3) + idx / mtiles; }
    else                  { nt = idx % ntiles; mt = xcd * (mtiles >> 3) + idx / ntiles; }
    const int m0 = mt * 256;
    const int n0 = nt * 256;
    const int wm = (wid >> 2) * 128;
    const int wn = (wid & 3) * 64;

    // staging: 32 chunk-ops of 1KB per tile (wave w gets ops g = w*4..w*4+3)
    const u16* gbase[4];
    u16* ldst[4];
    #pragma unroll
    for (int o = 0; o < 4; ++o) {
        int g = wid * 4 + o;
        int p = g >> 4;                  // 0 = A plane, 1 = B plane
        int j = ((g & 15) << 6) | lane;
        int c = j ^ ((j >> 3) & 3);
        int row = c >> 2, q = c & 3;
        const u16* base = (p == 0) ? A : B;
        int rbase = (p == 0) ? m0 : n0;
        gbase[o] = base + (size_t)(rbase + row) * K + q * 8;
        ldst[o] = &lds[0][0][0] + (size_t)p * 8192 + (size_t)j * 8;
    }

#define STG(KT, BUF)                                                             \
    {                                                                            \
        _Pragma("unroll")                                                        \
        for (int o = 0; o < 4; ++o)                                              \
            gload16(gbase[o] + (size_t)(KT) * 32, ldst[o] + (BUF) * 16384);      \
    }

    f32x4 acc[8][4] = {};
    const int KT = K >> 5;

    // prologue: stage tiles 0..2; wait for tile 0 only (8 newest may fly)
    STG(0, 0);
    STG(1, 1);
    STG(2, 2);
    asm volatile("s_waitcnt vmcnt(8)" ::: "memory");
    __builtin_amdgcn_s_barrier();

    for (int kt = 0; kt < KT; ++kt) {
        const u16* lb = &lds[kt & 3][0][0];
        // issue stage for tile kt+3 first: longest latency cover
        if (kt + 3 < KT) STG(kt + 3, (kt + 3) & 3);

        half8 b[4];
        #pragma unroll
        for (int j = 0; j < 4; ++j) {
            int s = swz((wn + (lane & 15) + j * 16) * 64 + (lane >> 4) * 16);
            b[j] = *(const half8*)(lb + 8192 + (s >> 1));
        }
        __builtin_amdgcn_s_setprio(1);
        #pragma unroll
        for (int ip = 0; ip < 4; ++ip) {
            int s0 = swz((wm + (lane & 15) + (2 * ip) * 16) * 64 + (lane >> 4) * 16);
            int s1 = swz((wm + (lane & 15) + (2 * ip + 1) * 16) * 64 + (lane >> 4) * 16);
            half8 a0 = *(const half8*)(lb + (s0 >> 1));
            half8 a1 = *(const half8*)(lb + (s1 >> 1));
            #pragma unroll
            for (int j = 0; j < 4; ++j) acc[2 * ip][j]     = MFMA_F16(a0, b[j], acc[2 * ip][j], 0, 0, 0);
            #pragma unroll
            for (int j = 0; j < 4; ++j) acc[2 * ip + 1][j] = MFMA_F16(a1, b[j], acc[2 * ip + 1][j], 0, 0, 0);
        }
        __builtin_amdgcn_s_setprio(0);
        // make buffer kt+1 ready: wait until only younger tiles' loads remain
        if (kt <= KT - 4)      { asm volatile("s_waitcnt vmcnt(8)" ::: "memory"); }
        else if (kt == KT - 3) { asm volatile("s_waitcnt vmcnt(4)" ::: "memory"); }
        else                   { asm volatile("s_waitcnt vmcnt(0)" ::: "memory"); }
        __builtin_amdgcn_s_barrier();
    }
#undef STG

    // epilogue: C/D layout = col (lane&15), row (lane>>4)*4 + e   [m89-verified]
    const int cb2 = n0 + wn + (lane & 15);
    #pragma unroll
    for (int i = 0; i < 8; ++i) {
        int rb = m0 + wm + i * 16 + ((lane >> 4) << 2);
        #pragma unroll
        for (int e = 0; e < 4; ++e) {
            if (F16OUT) {
                u16* crow = (u16*)Cv + (size_t)(rb + e) * ldc + cb2;
                #pragma unroll
                for (int j = 0; j < 4; ++j)
                    crow[j * 16] = f2h(acc[i][j][e]);
            } else {
                float* crow = (float*)Cv + (size_t)(rb + e) * ldc + cb2;
                #pragma unroll
                for (int j = 0; j < 4; ++j)
                    crow[j * 16] = acc[i][j][e];
            }
        }
    }
}

// ---------------- twiddle table init (global, shared by all FFT blocks) -------
__global__ __launch_bounds__(256)
void twiddle_init_kernel(float2* __restrict__ Tg) {
    int idx = blockIdx.x * 256 + threadIdx.x;
    if (idx >= 3072) return;
    float cs = 1.f, sn = 0.f;
    if (idx >= 2048) {
        sincosf(PI_F * (float)(idx - 2048) * (1.0f / 2048.0f), &sn, &cs);
    } else if (idx >= 1) {
        int s = 31 - __clz(idx);
        int h = 1 << s;
        sincosf(PI_F * (float)(idx - h) / (float)h, &sn, &cs);
    }
    Tg[idx] = make_float2(cs, sn);
}

// ---- packed-f32 butterflies: a,b are (re,im); compiles to v_pk_*_f32 ----
__device__ __forceinline__ void bfly_f(f32x2& a, f32x2& b, float cs, float sn) {
    f32x2 s = a + b;
    f32x2 d = a - b;
    f32x2 dsw = __builtin_shufflevector(d, d, 1, 0);   // (im, re)
    a = s;
    b = d * cs + dsw * (f32x2){sn, -sn};   // (dr*cs+di*sn, di*cs-dr*sn)
}
__device__ __forceinline__ void bfly_i(f32x2& a, f32x2& b, float cs, float sn) {
    f32x2 bsw = __builtin_shufflevector(b, b, 1, 0);   // (im, re)
    f32x2 c = b * cs + bsw * (f32x2){-sn, sn};         // b * e^{+i th}
    b = a - c;
    a = a + c;
}
// pad-based LDS index map: 2 float2 of pad per 32 elements.
__device__ __forceinline__ int IDX(int a) { return a + 2 * (a >> 5); }

// ---------------- fused rfft -> gates -> modReLU -> irfft, in-place f16 ------
__global__ __launch_bounds__(256)
void fft_gates_kernel(u16* __restrict__ vbuf, const float* __restrict__ gri,
                      const float* __restrict__ modb, const float2* __restrict__ Tg) {
    __shared__ f32x2 cf[2176];   // 2048 + 128 pad
    const int t = threadIdx.x;
    const int w = blockIdx.x;
    const int b = w & 3;
    u16* seq = vbuf + (size_t)w * SS;

    const int t5 = t & 31;
    const int t3 = t & 3;
    const int c32 = ((t >> 5) << 8) | t5;    // base for 32-span group
    const int d4  = ((t >> 2) << 5) | t3;    // base for 4-span group

    f32x2 r[8];

    // ---- load (f16 pairs) + G1: stages 10,9,8 (span 256) ----
    #pragma unroll
    for (int u = 0; u < 8; ++u) {
        ushort2 v = ((const ushort2*)seq)[t + 256 * u];
        r[u] = (f32x2){h2f(v.x), h2f(v.y)};
    }
    #pragma unroll
    for (int u = 0; u < 4; ++u) {
        float2 tw = Tg[1024 + t + 256 * u];
        bfly_f(r[u], r[u + 4], tw.x, tw.y);
    }
    {
        float2 tw0 = Tg[512 + t], tw1 = Tg[512 + t + 256];
        bfly_f(r[0], r[2], tw0.x, tw0.y);
        bfly_f(r[1], r[3], tw1.x, tw1.y);
        bfly_f(r[4], r[6], tw0.x, tw0.y);
        bfly_f(r[5], r[7], tw1.x, tw1.y);
        float2 tw = Tg[256 + t];
        bfly_f(r[0], r[1], tw.x, tw.y);
        bfly_f(r[2], r[3], tw.x, tw.y);
        bfly_f(r[4], r[5], tw.x, tw.y);
        bfly_f(r[6], r[7], tw.x, tw.y);
    }
    #pragma unroll
    for (int u = 0; u < 8; ++u) cf[IDX(t + 256 * u)] = r[u];
    __syncthreads();

    // ---- G2: stages 7,6,5 (span 32) ----
    #pragma unroll
    for (int u = 0; u < 8; ++u) r[u] = cf[IDX(c32 + 32 * u)];
    #pragma unroll
    for (int u = 0; u < 4; ++u) {
        float2 tw = Tg[128 + t5 + 32 * u];
        bfly_f(r[u], r[u + 4], tw.x, tw.y);
    }
    {
        float2 tw0 = Tg[64 + t5], tw1 = Tg[64 + t5 + 32];
        bfly_f(r[0], r[2], tw0.x, tw0.y);
        bfly_f(r[1], r[3], tw1.x, tw1.y);
        bfly_f(r[4], r[6], tw0.x, tw0.y);
        bfly_f(r[5], r[7], tw1.x, tw1.y);
        float2 tw = Tg[32 + t5];
        bfly_f(r[0], r[1], tw.x, tw.y);
        bfly_f(r[2], r[3], tw.x, tw.y);
        bfly_f(r[4], r[5], tw.x, tw.y);
        bfly_f(r[6], r[7], tw.x, tw.y);
    }
    #pragma unroll
    for (int u = 0; u < 8; ++u) cf[IDX(c32 + 32 * u)] = r[u];
    __syncthreads();

    // ---- G3: stages 4,3,2 (span 4) ----
    {
        f32x2* p3 = &cf[IDX(d4)];
        #pragma unroll
        for (int u = 0; u < 8; ++u) r[u] = p3[4 * u];
        #pragma unroll
        for (int u = 0; u < 4; ++u) {
            float2 tw = Tg[16 + t3 + 4 * u];
            bfly_f(r[u], r[u + 4], tw.x, tw.y);
        }
        {
            float2 tw0 = Tg[8 + t3], tw1 = Tg[8 + t3 + 4];
            bfly_f(r[0], r[2], tw0.x, tw0.y);
            bfly_f(r[1], r[3], tw1.x, tw1.y);
            bfly_f(r[4], r[6], tw0.x, tw0.y);
            bfly_f(r[5], r[7], tw1.x, tw1.y);
            float2 tw = Tg[4 + t3];
            bfly_f(r[0], r[1], tw.x, tw.y);
            bfly_f(r[2], r[3], tw.x, tw.y);
            bfly_f(r[4], r[5], tw.x, tw.y);
            bfly_f(r[6], r[7], tw.x, tw.y);
        }
        #pragma unroll
        for (int u = 0; u < 8; ++u) p3[4 * u] = r[u];
    }
    __syncthreads();

    // ---- G4: stages 1,0 (span 1; 8 consecutive -> b128-able) ----
    {
        f32x2* p4 = &cf[IDX(8 * t)];
        #pragma unroll
        for (int u = 0; u < 8; ++u) r[u] = p4[u];
        bfly_f(r[0], r[2], 1.f, 0.f);
        bfly_f(r[1], r[3], 0.f, 1.f);
        bfly_f(r[4], r[6], 1.f, 0.f);
        bfly_f(r[5], r[7], 0.f, 1.f);
        bfly_f(r[0], r[1], 1.f, 0.f);
        bfly_f(r[2], r[3], 1.f, 0.f);
        bfly_f(r[4], r[5], 1.f, 0.f);
        bfly_f(r[6], r[7], 1.f, 0.f);
        #pragma unroll
        for (int u = 0; u < 8; ++u) p4[u] = r[u];
    }
    __syncthreads();

    // ---- spectrum: unpack real-FFT bins (ortho /64), gates, modReLU, repack ----
    const float bias = modb[0];
    const float* gre = gri + (size_t)b * 2 * NFREQ;
    const float* gim = gre + NFREQ;
    const float inv64 = 1.0f / 64.0f;
    for (int k = t; k < 1024; k += 256) {
        if (k == 0) {
            f32x2 c0 = cf[IDX(0)];
            float z0 = (c0.x + c0.y) * inv64;
            float zM = (c0.x - c0.y) * inv64;
            float zr = z0 * gre[0], zi = z0 * gim[0];
            modrelu_apply(zr, zi, bias);
            float yr = zM * gre[2048], yi = zM * gim[2048];
            modrelu_apply(yr, yi, bias);
            cf[IDX(0)] = (f32x2){0.5f * (zr + yr), 0.5f * (zr - yr)};
            f32x2 c1 = cf[IDX(1)];
            float z1r = c1.x * inv64, z1i = -c1.y * inv64;
            float g1r = gre[1024], g1i = gim[1024];
            float pr = z1r * g1r - z1i * g1i;
            float pi2 = z1r * g1i + z1i * g1r;
            modrelu_apply(pr, pi2, bias);
            cf[IDX(1)] = (f32x2){pr, -pi2};
        } else {
            int kb = 2048 - k;
            int p1 = IDX((int)(__brev((unsigned)k) >> 21));
            int p2 = IDX((int)(__brev((unsigned)kb) >> 21));
            f32x2 ca = cf[p1];
            f32x2 cb2 = cf[p2];
            float Er = 0.5f * (ca.x + cb2.x), Ei = 0.5f * (ca.y - cb2.y);
            float Dr = 0.5f * (ca.x - cb2.x), Di = 0.5f * (ca.y + cb2.y);
            float Or = Di, Oi = -Dr;
            float2 t2 = Tg[2048 + k];
            float cs = t2.x, sn = t2.y;
            float Wr = cs, Wi = -sn;
            float WOr = Wr * Or - Wi * Oi, WOi = Wr * Oi + Wi * Or;
            float zkr = (Er + WOr) * inv64, zki = (Ei + WOi) * inv64;
            float zbr = (Er - WOr) * inv64, zbi = -(Ei - WOi) * inv64;
            float gkr = gre[k], gki = gim[k];
            float ar = zkr * gkr - zki * gki, ai = zkr * gki + zki * gkr;
            modrelu_apply(ar, ai, bias);
            float gbr = gre[kb], gbi = gim[kb];
            float br2 = zbr * gbr - zbi * gbi, bi2 = zbr * gbi + zbi * gbr;
            modrelu_apply(br2, bi2, bias);
            float Epr = 0.5f * (ar + br2), Epi = 0.5f * (ai - bi2);
            float Dpr = 0.5f * (ar - br2), Dpi = 0.5f * (ai + bi2);
            float Opr = cs * Dpr - sn * Dpi, Opi = cs * Dpi + sn * Dpr;
            cf[p1] = (f32x2){Epr - Opi, Epi + Opr};
            cf[p2] = (f32x2){Epr + Opi, -Epi + Opr};
        }
    }
    __syncthreads();

    // ---- inverse G4': stages 0,1 ----
    {
        f32x2* p4 = &cf[IDX(8 * t)];
        #pragma unroll
        for (int u = 0; u < 8; ++u) r[u] = p4[u];
        bfly_i(r[0], r[1], 1.f, 0.f);
        bfly_i(r[2], r[3], 1.f, 0.f);
        bfly_i(r[4], r[5], 1.f, 0.f);
        bfly_i(r[6], r[7], 1.f, 0.f);
        bfly_i(r[0], r[2], 1.f, 0.f);
        bfly_i(r[1], r[3], 0.f, 1.f);
        bfly_i(r[4], r[6], 1.f, 0.f);
        bfly_i(r[5], r[7], 0.f, 1.f);
        #pragma unroll
        for (int u = 0; u < 8; ++u) p4[u] = r[u];
    }
    __syncthreads();

    // ---- inverse G3': stages 2,3,4 ----
    {
        f32x2* p3 = &cf[IDX(d4)];
        #pragma unroll
        for (int u = 0; u < 8; ++u) r[u] = p3[4 * u];
        {
            float2 tw = Tg[4 + t3];
            bfly_i(r[0], r[1], tw.x, tw.y);
            bfly_i(r[2], r[3], tw.x, tw.y);
            bfly_i(r[4], r[5], tw.x, tw.y);
            bfly_i(r[6], r[7], tw.x, tw.y);
            float2 tw0 = Tg[8 + t3], tw1 = Tg[8 + t3 + 4];
            bfly_i(r[0], r[2], tw0.x, tw0.y);
            bfly_i(r[1], r[3], tw1.x, tw1.y);
            bfly_i(r[4], r[6], tw0.x, tw0.y);
            bfly_i(r[5], r[7], tw1.x, tw1.y);
        }
        #pragma unroll
        for (int u = 0; u < 4; ++u) {
            float2 tw = Tg[16 + t3 + 4 * u];
            bfly_i(r[u], r[u + 4], tw.x, tw.y);
        }
        #pragma unroll
        for (int u = 0; u < 8; ++u) p3[4 * u] = r[u];
    }
    __syncthreads();

    // ---- inverse G2': stages 5,6,7 ----
    #pragma unroll
    for (int u = 0; u < 8; ++u) r[u] = cf[IDX(c32 + 32 * u)];
    {
        float2 tw = Tg[32 + t5];
        bfly_i(r[0], r[1], tw.x, tw.y);
        bfly_i(r[2], r[3], tw.x, tw.y);
        bfly_i(r[4], r[5], tw.x, tw.y);
        bfly_i(r[6], r[7], tw.x, tw.y);
        float2 tw0 = Tg[64 + t5], tw1 = Tg[64 + t5 + 32];
        bfly_i(r[0], r[2], tw0.x, tw0.y);
        bfly_i(r[1], r[3], tw1.x, tw1.y);
        bfly_i(r[4], r[6], tw0.x, tw0.y);
        bfly_i(r[5], r[7], tw1.x, tw1.y);
    }
    #pragma unroll
    for (int u = 0; u < 4; ++u) {
        float2 tw = Tg[128 + t5 + 32 * u];
        bfly_i(r[u], r[u + 4], tw.x, tw.y);
    }
    #pragma unroll
    for (int u = 0; u < 8; ++u) cf[IDX(c32 + 32 * u)] = r[u];
    __syncthreads();

    // ---- inverse G1': stages 8,9,10 + scale + f16 store ----
    #pragma unroll
    for (int u = 0; u < 8; ++u) r[u] = cf[IDX(t + 256 * u)];
    {
        float2 tw = Tg[256 + t];
        bfly_i(r[0], r[1], tw.x, tw.y);
        bfly_i(r[2], r[3], tw.x, tw.y);
        bfly_i(r[4], r[5], tw.x, tw.y);
        bfly_i(r[6], r[7], tw.x, tw.y);
        float2 tw0 = Tg[512 + t], tw1 = Tg[512 + t + 256];
        bfly_i(r[0], r[2], tw0.x, tw0.y);
        bfly_i(r[1], r[3], tw1.x, tw1.y);
        bfly_i(r[4], r[6], tw0.x, tw0.y);
        bfly_i(r[5], r[7], tw1.x, tw1.y);
    }
    #pragma unroll
    for (int u = 0; u < 4; ++u) {
        float2 tw = Tg[1024 + t + 256 * u];
        bfly_i(r[u], r[u + 4], tw.x, tw.y);
    }
    const float s32 = 1.0f / 32.0f;  // 64 (ortho) / 2048 (ifft norm)
    #pragma unroll
    for (int u = 0; u < 8; ++u) {
        ushort2 o;
        o.x = f2h(r[u].x * s32);
        o.y = f2h(r[u].y * s32);
        ((ushort2*)seq)[t + 256 * u] = o;
    }
}

extern "C" void kernel_launch(void* const* d_in, const int* in_sizes, int n_in,
                              void* d_out, int out_size, void* d_ws, size_t ws_size,
                              hipStream_t stream) {
    const float* x        = (const float*)d_in[0];
    const float* W_q      = (const float*)d_in[1];
    const float* W_v      = (const float*)d_in[2];
    const float* W_o      = (const float*)d_in[3];
    const float* ln_gamma = (const float*)d_in[4];
    const float* ln_beta  = (const float*)d_in[5];
    const float* mlp_w1   = (const float*)d_in[6];
    const float* mlp_b1   = (const float*)d_in[7];
    const float* mlp_w2   = (const float*)d_in[8];
    const float* mlp_b2   = (const float*)d_in[9];
    const float* mod_bias = (const float*)d_in[10];
    float* out = (float*)d_out;

    // workspace layout (floats)
    float* ws = (float*)d_ws;
    float* partial  = ws;                    // 1048576 (1024 blocks x 1024)
    float* xsum     = ws + 1048576;          // 4096
    float* q_shared = ws + 1052672;          // 256
    float* hdn      = ws + 1052928;          // 4096
    float* gri      = ws + 1057024;          // 16392
    float* mq       = ws + 1073416;          // 4096 (ends 1077512)
    float2* twid    = (float2*)(ws + 1077512); // 3072 float2 (ends 1083656)
    u16* bfbase = (u16*)(ws + 1083904);
    u16* xut_f  = bfbase;                    // 16777216 u16: x_f16, later reused as ut
    u16* vbuf   = bfbase + 16777216;         // f16 V then u, [1024][16384] in-place fft
    u16* wv_f   = bfbase + 33554432;         // 1048576
    u16* wo_f   = bfbase + 34603008;         // 1048576

    twiddle_init_kernel<<<12, 256, 0, stream>>>(twid);

    // fused x f16-convert + colsum pass 1
    split_x_colsum_kernel<<<1024, 256, 0, stream>>>(x, xut_f, partial);
    {
        dim3 g(4, 4);
        colsum2_kernel<<<g, 256, 0, stream>>>(partial, xsum);
    }
    gates1a_kernel<<<256, 256, 0, stream>>>(xsum, W_q, mq);
    gates1b_kernel<<<4, 256, 0, stream>>>(mq, ln_gamma, ln_beta, q_shared);
    gates2_kernel<<<16, 256, 0, stream>>>(q_shared, mlp_w1, mlp_b1, hdn);
    gates3_kernel<<<1025, 256, 0, stream>>>(hdn, mlp_w2, mlp_b2, gri);

    // weight f16 conversions (both matrices, one launch)
    cvt_f16_dual_kernel<<<1024, 256, 0, stream>>>(W_v, wv_f, W_o, wo_f, 262144);

    // V projection (transposed output), f16 in/out: vbuf[j][bs] = Wv[j,:]·x[bs,:]
    // M=1024 (j), N=16384 (bs): mtiles=4, ntiles=64 -> 256 blocks
    gemm_f16_kernel<true><<<256, 512, 0, stream>>>(wv_f, xut_f,
                                                   vbuf, 4, 64, 1024, 16384);

    // fused spectral mixing, in place on vbuf (f16 -> f16)
    fft_gates_kernel<<<4096, 256, 0, stream>>>(vbuf, gri, mod_bias, twid);

    // transpose u: vbuf [1024][16384] -> xut_f [16384][1024] (pure u16 permute)
    {
        dim3 g(256, 16);
        transpose_u16_kernel<<<g, 256, 0, stream>>>(vbuf, xut_f);
    }

    // O projection, f16 in / f32 out: out[bs][jo] = ut[bs,:]·Wo[jo,:]
    // M=16384 (bs), N=1024 (jo): mtiles=64, ntiles=4 -> 256 blocks
    gemm_f16_kernel<false><<<256, 512, 0, stream>>>(xut_f, wo_f,
                                                    out, 64, 4, 1024, 1024);
}